// Round 6
// baseline (7936.697 us; speedup 1.0000x reference)
//
#include <hip/hip_runtime.h>
#include <hip/hip_bf16.h>
#include <stdint.h>
#include <cstdio>
#include <math.h>

// ---------------------------------------------------------------------------
// SpikingTradingAgent on MI355X — round 6.
// Numerics FROZEN (rounds 4/5 passed, absmax 1.07e-2): f32-faithful
// sequential-i einsum chain, f32 membrane update in reference op order,
// -0.0 refractory encoding, CR-exp sigmoid encoder, ballot spike bits.
//
// Round-6 change (scheduling only, bit-identical arithmetic): t-tiling.
// The 32 per-t i-chains are independent feed-forward sums; the membrane
// recurrence couples t only in the cheap update step. k_lif now processes
// 8 t-steps per i-pass with acc[8t][8h]:
//   - each W row s_load'ed once per 8 t (was once per t)     -> 8x less
//   - masks one s_load_dwordx16 per i (8 packed u64)          scalar traffic
//   - W repacked [p][h/8][i][8] (contiguous rows, K$ streaming)
//   - masks packed [bw][tg][i][8]
// Per-(b,h,t) fmaf chain order and membrane update unchanged.
// ---------------------------------------------------------------------------

typedef unsigned int u32;
typedef unsigned long long u64;

// workspace layout (bytes)
#define ENCT_OFF 0u                       // f32 [512][4096] (transposed)  8 MiB
#define BITS_OFF (8u << 20)               // u64 [64][4][512][8]           8 MiB
#define WT_OFF   (16u << 20)              // f32 [4][128][512][8]          8 MiB
#define CB_OFF   (24u << 20)              // u32 [4][4096][1024]          64 MiB
#define HID_OFF  (88u << 20)              // f32 [4096][512]               8 MiB
#define WS_NEED  ((size_t)HID_OFF + (8u << 20))

// d_out layout (floats): out0 [4096][3] @0, out1 [4096][4] @12288,
// out2 (mean_spike_rate) [4096][1024] @28672
#define OUT1_F 12288
#define OUT2_F 28672

// ---------------------------------------------------------------------------
// Encoder, f32-faithful: z = x @ enc_W, k-sequential FMA chains, kc=384 panel
// split, + bias, sigmoid via CR expf. Output transposed enc_T[i][b].
// ---------------------------------------------------------------------------
__global__ __launch_bounds__(64) void k_genc(const float* __restrict__ x,
                                             const float* __restrict__ W,
                                             const float* __restrict__ bias,
                                             float* __restrict__ encT) {
  const int lane = threadIdx.x;
  const int bg = blockIdx.x & 63;   // b-group of 64
  const int jg = blockIdx.x >> 6;   // j-group of 8 (64 groups)
  const int b = bg * 64 + lane;
  const int j0 = jg * 8;
  const float* xr = x + (size_t)b * 512;
  float accA[8], accB[8];
#pragma unroll
  for (int u = 0; u < 8; ++u) { accA[u] = 0.0f; accB[u] = 0.0f; }
  for (int k = 0; k < 384; ++k) {
    float xv = xr[k];
#pragma unroll
    for (int u = 0; u < 8; ++u) accA[u] = fmaf(xv, W[k * 512 + j0 + u], accA[u]);
  }
  for (int k = 384; k < 512; ++k) {
    float xv = xr[k];
#pragma unroll
    for (int u = 0; u < 8; ++u) accB[u] = fmaf(xv, W[k * 512 + j0 + u], accB[u]);
  }
#pragma unroll
  for (int u = 0; u < 8; ++u) {
    float z = __fadd_rn(__fadd_rn(accA[u], accB[u]), bias[j0 + u]);
    float ef = (float)exp(-(double)z);          // == correctly-rounded expf
    float enc = 1.0f / (1.0f + ef);
    encT[(size_t)(j0 + u) * 4096 + b] = enc;
  }
}

// ---------------------------------------------------------------------------
// Spike bits -> packed [bw][tg][i][8t]: word (bw,tg,i,tt) bit b =
// (noise[b][t][i] < enc[b][i]) f32, t = tg*8+tt. lane = b -> ballot.
// ---------------------------------------------------------------------------
__global__ __launch_bounds__(64) void k_spike(const float* __restrict__ noise,
                                              const float* __restrict__ encT,
                                              u64* __restrict__ bitsP) {
  const int lane = threadIdx.x;
  const int t = blockIdx.x & 31;
  const int bw = blockIdx.x >> 5;   // 64 b-waves
  const int b = bw * 64 + lane;
  const float* nr = noise + ((size_t)b * 32 + t) * 512;
  u64* dst = bitsP + (((size_t)bw * 4 + (t >> 3)) * 512) * 8 + (t & 7);
  for (int i0 = 0; i0 < 512; i0 += 4) {
    float4 nv = *(const float4*)(nr + i0);
    float e0 = encT[(size_t)(i0 + 0) * 4096 + b];
    float e1 = encT[(size_t)(i0 + 1) * 4096 + b];
    float e2 = encT[(size_t)(i0 + 2) * 4096 + b];
    float e3 = encT[(size_t)(i0 + 3) * 4096 + b];
    u64 m0 = __ballot(nv.x < e0);
    u64 m1 = __ballot(nv.y < e1);
    u64 m2 = __ballot(nv.z < e2);
    u64 m3 = __ballot(nv.w < e3);
    if (lane == 0) {
      dst[(i0 + 0) * 8] = m0; dst[(i0 + 1) * 8] = m1;
      dst[(i0 + 2) * 8] = m2; dst[(i0 + 3) * 8] = m3;
    }
  }
}

// ---------------------------------------------------------------------------
// W repack: Wt[p][hs][i][8] = lif_W[p][i][hs*8 .. hs*8+7]
// ---------------------------------------------------------------------------
__global__ __launch_bounds__(256) void k_wrep(const float* __restrict__ lifW,
                                              float* __restrict__ Wt) {
  int idx = blockIdx.x * 256 + threadIdx.x;   // 262144 = 4p x 128hs x 512i
  int i = idx & 511;
  int hs = (idx >> 9) & 127;
  int p = idx >> 16;
  const float* src = lifW + ((size_t)(p * 512 + i)) * 1024 + hs * 8;
  float4 a = *(const float4*)src;
  float4 c = *(const float4*)(src + 4);
  float* dst = Wt + (((size_t)(p * 128 + hs)) * 512 + (size_t)i) * 8;
  *(float4*)dst = a;
  *(float4*)(dst + 4) = c;
}

// ---------------------------------------------------------------------------
// pathway selection: softmax(x @ sel_W + sel_b) -> out1 f32
// ---------------------------------------------------------------------------
__global__ __launch_bounds__(256) void k_sel(const float* __restrict__ x,
                                             const float* __restrict__ selW,
                                             const float* __restrict__ selB,
                                             float* __restrict__ out1) {
  int b = blockIdx.x * 256 + threadIdx.x;
  const float* xr = x + (size_t)b * 512;
  double a0 = 0, a1 = 0, a2 = 0, a3 = 0;
  for (int k = 0; k < 512; ++k) {
    double xv = (double)xr[k];
    float4 w = *(const float4*)(selW + k * 4);
    a0 = fma(xv, (double)w.x, a0);
    a1 = fma(xv, (double)w.y, a1);
    a2 = fma(xv, (double)w.z, a2);
    a3 = fma(xv, (double)w.w, a3);
  }
  a0 += (double)selB[0]; a1 += (double)selB[1];
  a2 += (double)selB[2]; a3 += (double)selB[3];
  double m = fmax(fmax(a0, a1), fmax(a2, a3));
  double e0 = exp(a0 - m), e1 = exp(a1 - m), e2 = exp(a2 - m), e3 = exp(a3 - m);
  double inv = 1.0 / (e0 + e1 + e2 + e3);
  float4 wf = {(float)(e0 * inv), (float)(e1 * inv), (float)(e2 * inv), (float)(e3 * inv)};
  *(float4*)(out1 + (size_t)b * 4) = wf;
}

// ---------------------------------------------------------------------------
// Fused LIF, f32-faithful, 8h x 8t wave tile. lane = b (64 b's).
// Per i: s_load_dwordx8 (W row, 32B) + s_load_dwordx16 (8 masks) ->
// 8 cndmask + 64 fmac. acc[tt][h] chains are the reference's sequential-i
// f32 chains, bit-identical. Membrane recurrence per 8-step group.
// ---------------------------------------------------------------------------
__global__ __launch_bounds__(64, 4) void k_lif(const float* __restrict__ Wt,
                                               const float* __restrict__ lifB,
                                               const u64* __restrict__ bitsP,
                                               u32* __restrict__ cb) {
  const int lane = threadIdx.x;
  const int bid = blockIdx.x;               // 32768 = 8 xcd x (64 slab x 64 bw)
  const int xcd = bid & 7;
  const int idx = bid >> 3;                 // 4096
  const int slab = xcd * 64 + (idx & 63);   // 0..511 == p*128 + hs
  const int bw = idx >> 6;                  // 0..63
  const int p = slab >> 7;
  const int h0 = (slab & 127) * 8;
  const int b0 = bw * 64;
  const float* wbase = Wt + (size_t)slab * 512 * 8;
  const u64* mbase = bitsP + ((size_t)bw * 4) * 512 * 8;
  const float* biasp = lifB + p * 1024 + h0;

  float mem[8], bias_r[8];
  u32 cbits[8];
#pragma unroll
  for (int h = 0; h < 8; ++h) {
    mem[h] = 0.0f; cbits[h] = 0u;
    bias_r[h] = biasp[h];
  }

#pragma unroll 1
  for (int tg = 0; tg < 4; ++tg) {
    float acc[8][8];
#pragma unroll
    for (int tt = 0; tt < 8; ++tt)
#pragma unroll
      for (int h = 0; h < 8; ++h) acc[tt][h] = 0.0f;

    const u64* mrow = mbase + (size_t)tg * 512 * 8;
#pragma unroll 2
    for (int i = 0; i < 512; ++i) {
      const float* wr = wbase + (size_t)i * 8;   // uniform -> s_load_dwordx8
      const u64* mr = mrow + (size_t)i * 8;      // uniform -> s_load_dwordx16
      float spf[8];
#pragma unroll
      for (int tt = 0; tt < 8; ++tt)
        asm("v_cndmask_b32 %0, 0, 1.0, %1" : "=v"(spf[tt]) : "s"(mr[tt]));
#pragma unroll
      for (int tt = 0; tt < 8; ++tt)
#pragma unroll
        for (int h = 0; h < 8; ++h)
          acc[tt][h] = fmaf(wr[h], spf[tt], acc[tt][h]);
    }
    // membrane update, reference op order (all f32, no contraction)
#pragma unroll
    for (int tt = 0; tt < 8; ++tt) {
      const int t = tg * 8 + tt;
#pragma unroll
      for (int h = 0; h < 8; ++h) {
        float c = __fadd_rn(acc[tt][h], bias_r[h]);
        float mo = mem[h];
        bool blocked = (__float_as_uint(mo) == 0x80000000u);
        float mn = __fadd_rn(__fmul_rn(mo, 0.9f), c);
        bool sp = (mn >= 1.0f) && (!blocked);
        mem[h] = sp ? -0.0f : mn;
        cbits[h] |= (sp ? 1u : 0u) << t;
      }
    }
  }
  // store: lane owns (b = b0+lane, h = h0..h0+7) -> 8 consecutive u32
  u32* dst = cb + ((size_t)p * 4096 + b0 + lane) * 1024 + h0;
  uint4 v0 = {cbits[0], cbits[1], cbits[2], cbits[3]};
  uint4 v1 = {cbits[4], cbits[5], cbits[6], cbits[7]};
  *(uint4*)dst = v0;
  *(uint4*)(dst + 4) = v1;
}

// ---------------------------------------------------------------------------
// msr[b][h]: faithful f32: per t: s = p-ascending chain; acc = fl(acc+s); /32.
// ---------------------------------------------------------------------------
__global__ __launch_bounds__(256) void k_reduce(const u32* __restrict__ cb,
                                                const float* __restrict__ w,
                                                float* __restrict__ msr) {
  int idx = blockIdx.x * 256 + threadIdx.x;  // 4194304
  int h = idx & 1023;
  int b = idx >> 10;
  float4 wv = *(const float4*)(w + (size_t)b * 4);
  u32 c0 = cb[((size_t)0 * 4096 + b) * 1024 + h];
  u32 c1 = cb[((size_t)1 * 4096 + b) * 1024 + h];
  u32 c2 = cb[((size_t)2 * 4096 + b) * 1024 + h];
  u32 c3 = cb[((size_t)3 * 4096 + b) * 1024 + h];
  float acc = 0.0f;
#pragma unroll
  for (int t = 0; t < 32; ++t) {
    float s = ((c0 >> t) & 1u) ? wv.x : 0.0f;
    s = __fadd_rn(s, ((c1 >> t) & 1u) ? wv.y : 0.0f);
    s = __fadd_rn(s, ((c2 >> t) & 1u) ? wv.z : 0.0f);
    s = __fadd_rn(s, ((c3 >> t) & 1u) ? wv.w : 0.0f);
    acc = __fadd_rn(acc, s);
  }
  msr[(size_t)b * 1024 + h] = acc * 0.03125f;  // /32 exact
}

// ---------------------------------------------------------------------------
// f32 GEMM + relu (head):  out = relu(A[M,K] @ W[K,N] + bias)
// ---------------------------------------------------------------------------
__global__ __launch_bounds__(256) void k_gemm_relu(const float* __restrict__ A, int lda,
                                                   const float* __restrict__ W, int ldw,
                                                   const float* __restrict__ bias,
                                                   float* __restrict__ out, int ldo, int K) {
  __shared__ float As[16][65];
  __shared__ float Bs[16][64];
  const int tid = threadIdx.x;
  const int tx = tid & 15, ty = tid >> 4;
  const int n0 = blockIdx.x * 64, m0 = blockIdx.y * 64;
  const int sm = tid >> 2, skq = tid & 3;
  float acc[4][4] = {};
  for (int k0 = 0; k0 < K; k0 += 16) {
    float4 av = *(const float4*)(A + (size_t)(m0 + sm) * lda + k0 + skq * 4);
    As[skq * 4 + 0][sm] = av.x;
    As[skq * 4 + 1][sm] = av.y;
    As[skq * 4 + 2][sm] = av.z;
    As[skq * 4 + 3][sm] = av.w;
#pragma unroll
    for (int j = 0; j < 4; ++j) {
      int k = j * 4 + (tid >> 6);
      int n = tid & 63;
      Bs[k][n] = W[(size_t)(k0 + k) * ldw + n0 + n];
    }
    __syncthreads();
#pragma unroll
    for (int k = 0; k < 16; ++k) {
      float a[4], bb[4];
#pragma unroll
      for (int i = 0; i < 4; ++i) a[i] = As[k][ty * 4 + i];
#pragma unroll
      for (int i = 0; i < 4; ++i) bb[i] = Bs[k][tx * 4 + i];
#pragma unroll
      for (int i = 0; i < 4; ++i)
#pragma unroll
        for (int ii = 0; ii < 4; ++ii) acc[i][ii] = fmaf(a[i], bb[ii], acc[i][ii]);
    }
    __syncthreads();
  }
#pragma unroll
  for (int i = 0; i < 4; ++i)
#pragma unroll
    for (int ii = 0; ii < 4; ++ii) {
      float v = fmaxf(acc[i][ii] + bias[n0 + tx * 4 + ii], 0.0f);
      out[(size_t)(m0 + ty * 4 + i) * ldo + n0 + tx * 4 + ii] = v;
    }
}

// ---------------------------------------------------------------------------
// out0 = hid @ out_W2 + b2   (one thread per b)
// ---------------------------------------------------------------------------
__global__ __launch_bounds__(256) void k_head2(const float* __restrict__ hid,
                                               const float* __restrict__ W2,
                                               const float* __restrict__ b2,
                                               float* __restrict__ out0) {
  __shared__ float w2s[512][3];
  int tid = threadIdx.x;
  for (int i = tid; i < 1536; i += 256) ((float*)w2s)[i] = W2[i];
  __syncthreads();
  int b = blockIdx.x * 256 + tid;
  const float* hr = hid + (size_t)b * 512;
  float a0 = 0, a1 = 0, a2 = 0;
  for (int j = 0; j < 512; ++j) {
    float h = hr[j];
    a0 = fmaf(h, w2s[j][0], a0);
    a1 = fmaf(h, w2s[j][1], a1);
    a2 = fmaf(h, w2s[j][2], a2);
  }
  out0[b * 3 + 0] = a0 + b2[0];
  out0[b * 3 + 1] = a1 + b2[1];
  out0[b * 3 + 2] = a2 + b2[2];
}

// ---------------------------------------------------------------------------
extern "C" void kernel_launch(void* const* d_in, const int* in_sizes, int n_in,
                              void* d_out, int out_size, void* d_ws, size_t ws_size,
                              hipStream_t stream) {
  const float* x = (const float*)d_in[0];
  const float* noise = (const float*)d_in[1];
  const float* encW = (const float*)d_in[3];
  const float* encB = (const float*)d_in[4];
  const float* selW = (const float*)d_in[5];
  const float* selB = (const float*)d_in[6];
  const float* lifW = (const float*)d_in[7];
  const float* lifB = (const float*)d_in[8];
  const float* W1 = (const float*)d_in[9];
  const float* b1 = (const float*)d_in[10];
  const float* W2 = (const float*)d_in[11];
  const float* b2 = (const float*)d_in[12];
  float* out = (float*)d_out;
  unsigned char* ws = (unsigned char*)d_ws;

  if (ws_size < WS_NEED) {
    fprintf(stderr, "kernel_launch: ws too small (%zu < %zu)\n", ws_size, (size_t)WS_NEED);
    return;
  }

  float* encT = (float*)(ws + ENCT_OFF);
  u64* bitsP = (u64*)(ws + BITS_OFF);
  float* Wt = (float*)(ws + WT_OFF);
  u32* cb = (u32*)(ws + CB_OFF);
  float* hid = (float*)(ws + HID_OFF);

  // 1. encoder (f32-faithful) -> enc_T
  k_genc<<<dim3(4096), 64, 0, stream>>>(x, encW, encB, encT);
  // 2. pathway weights -> out1 (f32)
  k_sel<<<dim3(16), 256, 0, stream>>>(x, selW, selB, out + OUT1_F);
  // 3. W repack [p][hs][i][8]
  k_wrep<<<dim3(1024), 256, 0, stream>>>(lifW, Wt);
  // 4. spike bits, f32 compare, ballot -> [bw][tg][i][8]
  k_spike<<<dim3(2048), 64, 0, stream>>>(noise, encT, bitsP);
  // 5. fused LIF, t-tiled sequential-i f32 chains (dominant)
  k_lif<<<dim3(32768), 64, 0, stream>>>(Wt, lifB, bitsP, cb);
  // 6. mean spike rate (faithful f32 p/t chains) -> out2
  k_reduce<<<dim3(16384), 256, 0, stream>>>(cb, out + OUT1_F, out + OUT2_F);
  // 7. hid = relu(msr @ W1 + b1)
  k_gemm_relu<<<dim3(8, 64), 256, 0, stream>>>(out + OUT2_F, 1024, W1, 512, b1, hid, 512, 1024);
  // 8. out0 = hid @ W2 + b2
  k_head2<<<dim3(16), 256, 0, stream>>>(hid, W2, b2, out);
}

// Round 8
// 6421.171 us; speedup vs baseline: 1.2360x; 1.2360x over previous
//
#include <hip/hip_runtime.h>
#include <hip/hip_bf16.h>
#include <stdint.h>
#include <cstdio>
#include <math.h>

// ---------------------------------------------------------------------------
// SpikingTradingAgent on MI355X — round 8.
// Numerics FROZEN (rounds 4-6 passed, absmax 1.07e-2): f32-faithful
// sequential-i einsum chain, f32 membrane update in reference op order,
// -0.0 refractory encoding, CR-exp sigmoid encoder, ballot spike bits.
//
// Round-8 change (scheduling only, bit-identical arithmetic):
// r5/r6 plateaued at ~64% VALUBusy independent of occupancy & s_load rate:
// SMEM is out-of-order, so every s_load use forces lgkmcnt(0) which also
// drains prefetched s_loads -> prefetch self-defeating. r7's raw-asm VMEM
// loads crashed (async outputs vs register allocator). This round: hot loop
// has ZERO SMEM / ZERO LDS / ZERO asm — pure in-order VMEM via plain C++:
//   k_expand: ballot words -> per-lane spike bytes spf[tg][i][b][tt] (64MB)
//   k_lif per i: 1 coalesced dwordx2 (8 spike bytes = 8 t) per lane
//              + 2 uniform float4 (W row) + 8 cvt_ubyte + 64 fmaf.
// Compiler pipelines VMEM with counted vmcnt(N) (in-order) reliably.
// ---------------------------------------------------------------------------

typedef unsigned int u32;
typedef unsigned long long u64;

// workspace layout (bytes)
#define ENCT_OFF 0u                        // f32 [512][4096]              8 MiB
#define BITS_OFF (8u << 20)                // u64 [64][4][512][8]          8 MiB
#define WT_OFF   (16u << 20)               // f32 [512][512][8]            8 MiB
#define SPF_OFF  (24u << 20)               // u8  [4][512][4096][8]       64 MiB
#define CB_OFF   (88u << 20)               // u32 [4][4096][1024]         64 MiB
#define HID_OFF  (152u << 20)              // f32 [4096][512]              8 MiB
#define WS_NEED  ((size_t)HID_OFF + (8u << 20))

// d_out layout (floats): out0 [4096][3] @0, out1 [4096][4] @12288,
// out2 (mean_spike_rate) [4096][1024] @28672
#define OUT1_F 12288
#define OUT2_F 28672

// ---------------------------------------------------------------------------
// Encoder, f32-faithful: z = x @ enc_W, k-sequential FMA chains, kc=384 panel
// split, + bias, sigmoid via CR expf. Output transposed enc_T[i][b].
// ---------------------------------------------------------------------------
__global__ __launch_bounds__(64) void k_genc(const float* __restrict__ x,
                                             const float* __restrict__ W,
                                             const float* __restrict__ bias,
                                             float* __restrict__ encT) {
  const int lane = threadIdx.x;
  const int bg = blockIdx.x & 63;   // b-group of 64
  const int jg = blockIdx.x >> 6;   // j-group of 8 (64 groups)
  const int b = bg * 64 + lane;
  const int j0 = jg * 8;
  const float* xr = x + (size_t)b * 512;
  float accA[8], accB[8];
#pragma unroll
  for (int u = 0; u < 8; ++u) { accA[u] = 0.0f; accB[u] = 0.0f; }
  for (int k = 0; k < 384; ++k) {
    float xv = xr[k];
#pragma unroll
    for (int u = 0; u < 8; ++u) accA[u] = fmaf(xv, W[k * 512 + j0 + u], accA[u]);
  }
  for (int k = 384; k < 512; ++k) {
    float xv = xr[k];
#pragma unroll
    for (int u = 0; u < 8; ++u) accB[u] = fmaf(xv, W[k * 512 + j0 + u], accB[u]);
  }
#pragma unroll
  for (int u = 0; u < 8; ++u) {
    float z = __fadd_rn(__fadd_rn(accA[u], accB[u]), bias[j0 + u]);
    float ef = (float)exp(-(double)z);          // == correctly-rounded expf
    float enc = 1.0f / (1.0f + ef);
    encT[(size_t)(j0 + u) * 4096 + b] = enc;
  }
}

// ---------------------------------------------------------------------------
// Spike bits -> packed [bw][tg][i][8t]: word (bw,tg,i,tt) bit b =
// (noise[b][t][i] < enc[b][i]) f32, t = tg*8+tt. lane = b -> ballot.
// ---------------------------------------------------------------------------
__global__ __launch_bounds__(64) void k_spike(const float* __restrict__ noise,
                                              const float* __restrict__ encT,
                                              u64* __restrict__ bitsP) {
  const int lane = threadIdx.x;
  const int t = blockIdx.x & 31;
  const int bw = blockIdx.x >> 5;   // 64 b-waves
  const int b = bw * 64 + lane;
  const float* nr = noise + ((size_t)b * 32 + t) * 512;
  u64* dst = bitsP + (((size_t)bw * 4 + (t >> 3)) * 512) * 8 + (t & 7);
  for (int i0 = 0; i0 < 512; i0 += 4) {
    float4 nv = *(const float4*)(nr + i0);
    float e0 = encT[(size_t)(i0 + 0) * 4096 + b];
    float e1 = encT[(size_t)(i0 + 1) * 4096 + b];
    float e2 = encT[(size_t)(i0 + 2) * 4096 + b];
    float e3 = encT[(size_t)(i0 + 3) * 4096 + b];
    u64 m0 = __ballot(nv.x < e0);
    u64 m1 = __ballot(nv.y < e1);
    u64 m2 = __ballot(nv.z < e2);
    u64 m3 = __ballot(nv.w < e3);
    if (lane == 0) {
      dst[(i0 + 0) * 8] = m0; dst[(i0 + 1) * 8] = m1;
      dst[(i0 + 2) * 8] = m2; dst[(i0 + 3) * 8] = m3;
    }
  }
}

// ---------------------------------------------------------------------------
// Expand ballot words to per-lane spike bytes:
// spf[((tg*512 + i)*4096 + b)*8 + tt] = bit b of bitsP[bw][tg][i][tt].
// Each lane (=b within bw) assembles a u64 (8 bytes = tt 0..7) per i and
// stores coalesced (stride 8B across lanes).
// ---------------------------------------------------------------------------
__global__ __launch_bounds__(64) void k_expand(const u64* __restrict__ bitsP,
                                               unsigned char* __restrict__ spf) {
  const int lane = threadIdx.x;
  const int bid = blockIdx.x;       // 2048 = bw(64) x tg(4) x ic(8)
  const int ic = bid & 7;
  const int tg = (bid >> 3) & 3;
  const int bw = bid >> 5;
  const u64* src = bitsP + (((size_t)bw * 4 + tg) * 512) * 8;
  for (int ii = 0; ii < 64; ++ii) {
    const int i = ic * 64 + ii;
    u64 w = 0;
#pragma unroll
    for (int tt = 0; tt < 8; ++tt) {
      u64 m = src[(size_t)i * 8 + tt];
      w |= ((m >> lane) & 1ULL) << (8 * tt);
    }
    *(u64*)(spf + ((size_t)(tg * 512 + i) * 4096 + bw * 64 + lane) * 8) = w;
  }
}

// ---------------------------------------------------------------------------
// W repack: Wt[slab][i][8] = lif_W[p][i][hs*8 .. hs*8+7], slab = p*128+hs
// ---------------------------------------------------------------------------
__global__ __launch_bounds__(256) void k_wrep(const float* __restrict__ lifW,
                                              float* __restrict__ Wt) {
  int idx = blockIdx.x * 256 + threadIdx.x;   // 262144 = 4p x 128hs x 512i
  int i = idx & 511;
  int hs = (idx >> 9) & 127;
  int p = idx >> 16;
  const float* src = lifW + ((size_t)(p * 512 + i)) * 1024 + hs * 8;
  float4 a = *(const float4*)src;
  float4 c = *(const float4*)(src + 4);
  float* dst = Wt + (((size_t)(p * 128 + hs)) * 512 + (size_t)i) * 8;
  *(float4*)dst = a;
  *(float4*)(dst + 4) = c;
}

// ---------------------------------------------------------------------------
// pathway selection: softmax(x @ sel_W + sel_b) -> out1 f32
// ---------------------------------------------------------------------------
__global__ __launch_bounds__(256) void k_sel(const float* __restrict__ x,
                                             const float* __restrict__ selW,
                                             const float* __restrict__ selB,
                                             float* __restrict__ out1) {
  int b = blockIdx.x * 256 + threadIdx.x;
  const float* xr = x + (size_t)b * 512;
  double a0 = 0, a1 = 0, a2 = 0, a3 = 0;
  for (int k = 0; k < 512; ++k) {
    double xv = (double)xr[k];
    float4 w = *(const float4*)(selW + k * 4);
    a0 = fma(xv, (double)w.x, a0);
    a1 = fma(xv, (double)w.y, a1);
    a2 = fma(xv, (double)w.z, a2);
    a3 = fma(xv, (double)w.w, a3);
  }
  a0 += (double)selB[0]; a1 += (double)selB[1];
  a2 += (double)selB[2]; a3 += (double)selB[3];
  double m = fmax(fmax(a0, a1), fmax(a2, a3));
  double e0 = exp(a0 - m), e1 = exp(a1 - m), e2 = exp(a2 - m), e3 = exp(a3 - m);
  double inv = 1.0 / (e0 + e1 + e2 + e3);
  float4 wf = {(float)(e0 * inv), (float)(e1 * inv), (float)(e2 * inv), (float)(e3 * inv)};
  *(float4*)(out1 + (size_t)b * 4) = wf;
}

// ---------------------------------------------------------------------------
// Fused LIF, f32-faithful, 8h x 8t wave tile, lane = b. Pure VMEM hot loop:
// per i: 1 per-lane dwordx2 (8 spike bytes), 2 uniform float4 (W row),
// 8 byte->float cvt, 64 fmaf. acc[tt][h] chains == reference sequential-i
// f32 chains (spf in {0.0f,1.0f}), bit-identical to rounds 4-6.
// ---------------------------------------------------------------------------
__global__ __launch_bounds__(64, 4) void k_lif(const float* __restrict__ Wt,
                                               const float* __restrict__ lifB,
                                               const unsigned char* __restrict__ spf,
                                               u32* __restrict__ cb) {
  const int lane = threadIdx.x;
  const int bid = blockIdx.x;          // 32768 = 64 bw x 512 slab
  const int slab = bid & 511;          // p*128 + hs (slab-major: blocks of one
  const int bw = bid >> 9;             //  bw run together -> spf L2-hot)
  const int p = slab >> 7;
  const int h0 = (slab & 127) * 8;
  const int b0 = bw * 64;
  const float* wbase = Wt + (size_t)slab * 512 * 8;
  const float* biasp = lifB + p * 1024 + h0;

  float mem[8], bias_r[8];
  u32 cbits[8];
#pragma unroll
  for (int h = 0; h < 8; ++h) {
    mem[h] = 0.0f; cbits[h] = 0u;
    bias_r[h] = biasp[h];
  }

#pragma unroll 1
  for (int tg = 0; tg < 4; ++tg) {
    float acc[8][8];
#pragma unroll
    for (int tt = 0; tt < 8; ++tt)
#pragma unroll
      for (int h = 0; h < 8; ++h) acc[tt][h] = 0.0f;

    const unsigned char* sb = spf + ((size_t)(tg * 512) * 4096 + b0 + lane) * 8;

#pragma unroll 2
    for (int i = 0; i < 512; ++i) {
      u64 sv = *(const u64*)(sb + (size_t)i * 32768);   // per-lane, coalesced
      float4 w0 = *(const float4*)(wbase + i * 8);      // uniform broadcast
      float4 w1 = *(const float4*)(wbase + i * 8 + 4);
      u32 lo = (u32)sv, hi = (u32)(sv >> 32);
      float s0 = (float)(lo & 0xffu);
      float s1 = (float)((lo >> 8) & 0xffu);
      float s2 = (float)((lo >> 16) & 0xffu);
      float s3 = (float)(lo >> 24);
      float s4 = (float)(hi & 0xffu);
      float s5 = (float)((hi >> 8) & 0xffu);
      float s6 = (float)((hi >> 16) & 0xffu);
      float s7 = (float)(hi >> 24);
      float sarr[8] = {s0, s1, s2, s3, s4, s5, s6, s7};
#pragma unroll
      for (int tt = 0; tt < 8; ++tt) {
        float sp = sarr[tt];
        acc[tt][0] = fmaf(w0.x, sp, acc[tt][0]);
        acc[tt][1] = fmaf(w0.y, sp, acc[tt][1]);
        acc[tt][2] = fmaf(w0.z, sp, acc[tt][2]);
        acc[tt][3] = fmaf(w0.w, sp, acc[tt][3]);
        acc[tt][4] = fmaf(w1.x, sp, acc[tt][4]);
        acc[tt][5] = fmaf(w1.y, sp, acc[tt][5]);
        acc[tt][6] = fmaf(w1.z, sp, acc[tt][6]);
        acc[tt][7] = fmaf(w1.w, sp, acc[tt][7]);
      }
    }
    // membrane update, reference op order (all f32, no contraction)
#pragma unroll
    for (int tt = 0; tt < 8; ++tt) {
      const int t = tg * 8 + tt;
#pragma unroll
      for (int h = 0; h < 8; ++h) {
        float c = __fadd_rn(acc[tt][h], bias_r[h]);
        float mo = mem[h];
        bool blocked = (__float_as_uint(mo) == 0x80000000u);
        float mn = __fadd_rn(__fmul_rn(mo, 0.9f), c);
        bool sp = (mn >= 1.0f) && (!blocked);
        mem[h] = sp ? -0.0f : mn;
        cbits[h] |= (sp ? 1u : 0u) << t;
      }
    }
  }
  // store: lane owns (b = b0+lane, h = h0..h0+7) -> 8 consecutive u32
  u32* dst = cb + ((size_t)p * 4096 + b0 + lane) * 1024 + h0;
  uint4 v0 = {cbits[0], cbits[1], cbits[2], cbits[3]};
  uint4 v1 = {cbits[4], cbits[5], cbits[6], cbits[7]};
  *(uint4*)dst = v0;
  *(uint4*)(dst + 4) = v1;
}

// ---------------------------------------------------------------------------
// msr[b][h]: faithful f32: per t: s = p-ascending chain; acc = fl(acc+s); /32.
// ---------------------------------------------------------------------------
__global__ __launch_bounds__(256) void k_reduce(const u32* __restrict__ cb,
                                                const float* __restrict__ w,
                                                float* __restrict__ msr) {
  int idx = blockIdx.x * 256 + threadIdx.x;  // 4194304
  int h = idx & 1023;
  int b = idx >> 10;
  float4 wv = *(const float4*)(w + (size_t)b * 4);
  u32 c0 = cb[((size_t)0 * 4096 + b) * 1024 + h];
  u32 c1 = cb[((size_t)1 * 4096 + b) * 1024 + h];
  u32 c2 = cb[((size_t)2 * 4096 + b) * 1024 + h];
  u32 c3 = cb[((size_t)3 * 4096 + b) * 1024 + h];
  float acc = 0.0f;
#pragma unroll
  for (int t = 0; t < 32; ++t) {
    float s = ((c0 >> t) & 1u) ? wv.x : 0.0f;
    s = __fadd_rn(s, ((c1 >> t) & 1u) ? wv.y : 0.0f);
    s = __fadd_rn(s, ((c2 >> t) & 1u) ? wv.z : 0.0f);
    s = __fadd_rn(s, ((c3 >> t) & 1u) ? wv.w : 0.0f);
    acc = __fadd_rn(acc, s);
  }
  msr[(size_t)b * 1024 + h] = acc * 0.03125f;  // /32 exact
}

// ---------------------------------------------------------------------------
// f32 GEMM + relu (head):  out = relu(A[M,K] @ W[K,N] + bias)
// ---------------------------------------------------------------------------
__global__ __launch_bounds__(256) void k_gemm_relu(const float* __restrict__ A, int lda,
                                                   const float* __restrict__ W, int ldw,
                                                   const float* __restrict__ bias,
                                                   float* __restrict__ out, int ldo, int K) {
  __shared__ float As[16][65];
  __shared__ float Bs[16][64];
  const int tid = threadIdx.x;
  const int tx = tid & 15, ty = tid >> 4;
  const int n0 = blockIdx.x * 64, m0 = blockIdx.y * 64;
  const int sm = tid >> 2, skq = tid & 3;
  float acc[4][4] = {};
  for (int k0 = 0; k0 < K; k0 += 16) {
    float4 av = *(const float4*)(A + (size_t)(m0 + sm) * lda + k0 + skq * 4);
    As[skq * 4 + 0][sm] = av.x;
    As[skq * 4 + 1][sm] = av.y;
    As[skq * 4 + 2][sm] = av.z;
    As[skq * 4 + 3][sm] = av.w;
#pragma unroll
    for (int j = 0; j < 4; ++j) {
      int k = j * 4 + (tid >> 6);
      int n = tid & 63;
      Bs[k][n] = W[(size_t)(k0 + k) * ldw + n0 + n];
    }
    __syncthreads();
#pragma unroll
    for (int k = 0; k < 16; ++k) {
      float a[4], bb[4];
#pragma unroll
      for (int i = 0; i < 4; ++i) a[i] = As[k][ty * 4 + i];
#pragma unroll
      for (int i = 0; i < 4; ++i) bb[i] = Bs[k][tx * 4 + i];
#pragma unroll
      for (int i = 0; i < 4; ++i)
#pragma unroll
        for (int ii = 0; ii < 4; ++ii) acc[i][ii] = fmaf(a[i], bb[ii], acc[i][ii]);
    }
    __syncthreads();
  }
#pragma unroll
  for (int i = 0; i < 4; ++i)
#pragma unroll
    for (int ii = 0; ii < 4; ++ii) {
      float v = fmaxf(acc[i][ii] + bias[n0 + tx * 4 + ii], 0.0f);
      out[(size_t)(m0 + ty * 4 + i) * ldo + n0 + tx * 4 + ii] = v;
    }
}

// ---------------------------------------------------------------------------
// out0 = hid @ out_W2 + b2   (one thread per b)
// ---------------------------------------------------------------------------
__global__ __launch_bounds__(256) void k_head2(const float* __restrict__ hid,
                                               const float* __restrict__ W2,
                                               const float* __restrict__ b2,
                                               float* __restrict__ out0) {
  __shared__ float w2s[512][3];
  int tid = threadIdx.x;
  for (int i = tid; i < 1536; i += 256) ((float*)w2s)[i] = W2[i];
  __syncthreads();
  int b = blockIdx.x * 256 + tid;
  const float* hr = hid + (size_t)b * 512;
  float a0 = 0, a1 = 0, a2 = 0;
  for (int j = 0; j < 512; ++j) {
    float h = hr[j];
    a0 = fmaf(h, w2s[j][0], a0);
    a1 = fmaf(h, w2s[j][1], a1);
    a2 = fmaf(h, w2s[j][2], a2);
  }
  out0[b * 3 + 0] = a0 + b2[0];
  out0[b * 3 + 1] = a1 + b2[1];
  out0[b * 3 + 2] = a2 + b2[2];
}

// ---------------------------------------------------------------------------
extern "C" void kernel_launch(void* const* d_in, const int* in_sizes, int n_in,
                              void* d_out, int out_size, void* d_ws, size_t ws_size,
                              hipStream_t stream) {
  const float* x = (const float*)d_in[0];
  const float* noise = (const float*)d_in[1];
  const float* encW = (const float*)d_in[3];
  const float* encB = (const float*)d_in[4];
  const float* selW = (const float*)d_in[5];
  const float* selB = (const float*)d_in[6];
  const float* lifW = (const float*)d_in[7];
  const float* lifB = (const float*)d_in[8];
  const float* W1 = (const float*)d_in[9];
  const float* b1 = (const float*)d_in[10];
  const float* W2 = (const float*)d_in[11];
  const float* b2 = (const float*)d_in[12];
  float* out = (float*)d_out;
  unsigned char* ws = (unsigned char*)d_ws;

  if (ws_size < WS_NEED) {
    fprintf(stderr, "kernel_launch: ws too small (%zu < %zu)\n", ws_size, (size_t)WS_NEED);
    return;
  }

  float* encT = (float*)(ws + ENCT_OFF);
  u64* bitsP = (u64*)(ws + BITS_OFF);
  float* Wt = (float*)(ws + WT_OFF);
  unsigned char* spf = ws + SPF_OFF;
  u32* cb = (u32*)(ws + CB_OFF);
  float* hid = (float*)(ws + HID_OFF);

  // 1. encoder (f32-faithful) -> enc_T
  k_genc<<<dim3(4096), 64, 0, stream>>>(x, encW, encB, encT);
  // 2. pathway weights -> out1 (f32)
  k_sel<<<dim3(16), 256, 0, stream>>>(x, selW, selB, out + OUT1_F);
  // 3. W repack [slab][i][8]
  k_wrep<<<dim3(1024), 256, 0, stream>>>(lifW, Wt);
  // 4. spike bits, f32 compare, ballot -> [bw][tg][i][tt]
  k_spike<<<dim3(2048), 64, 0, stream>>>(noise, encT, bitsP);
  // 5. expand ballots to per-lane spike bytes [tg][i][b][tt]
  k_expand<<<dim3(2048), 64, 0, stream>>>(bitsP, spf);
  // 6. fused LIF, pure-VMEM pipelined (dominant)
  k_lif<<<dim3(32768), 64, 0, stream>>>(Wt, lifB, spf, cb);
  // 7. mean spike rate (faithful f32 p/t chains) -> out2
  k_reduce<<<dim3(16384), 256, 0, stream>>>(cb, out + OUT1_F, out + OUT2_F);
  // 8. hid = relu(msr @ W1 + b1)
  k_gemm_relu<<<dim3(8, 64), 256, 0, stream>>>(out + OUT2_F, 1024, W1, 512, b1, hid, 512, 1024);
  // 9. out0 = hid @ W2 + b2
  k_head2<<<dim3(16), 256, 0, stream>>>(hid, W2, b2, out);
}